// Round 3
// baseline (134.610 us; speedup 1.0000x reference)
//
#include <hip/hip_runtime.h>

// Shapes (fixed by the reference):
//   frames: (4, 8, 256, 256, 1) f32
//   core:   (4, 256, 256, 200)  f32  -> raw-reshaped to (4, 8, 256, 256, 1, 25)
//   out:    pred_img (4,256,256,1) ++ pred_img_i (4,8,256,256,1), f32
//
// Fused single kernel: block = (b, y, half-row of 128 px) x ALL 8 burst frames.
//   n = tid>>5, q = tid&31 (4 px per thread). Computes pred_img_i for all n,
//   then block-level LDS reduction produces pred_img -> no second kernel, and
//   pred_img_i is write-only (its 8.4 MB HBM re-read is eliminated).
// core (210 MB, zero reuse) is read nontemporally; outputs stored nontemporally.
#define H 256
#define W 256

typedef float f4 __attribute__((ext_vector_type(4)));

__global__ __launch_bounds__(256, 3)
void kpn_fused(const float* __restrict__ frames, const float* __restrict__ core,
               float* __restrict__ pred, float* __restrict__ pred_i) {
  // frame staging [n][r][c]: 8 frames x 5 rows x 34 float4 (x = xh*128-4 .. +131)
  __shared__ f4 smem[8 * 5 * 34];      // 21760 B; first 256 slots reused for reduction

  const int tid = threadIdx.x;
  const int blk = blockIdx.x;          // b*512 + y*2 + xh
  const int xh  = blk & 1;
  const int y   = (blk >> 1) & 255;
  const int b   = blk >> 9;

  const int n = tid >> 5;              // burst frame 0..7
  const int q = tid & 31;              // 4-pixel group within the 128-px half-row

  // ---- issue ALL 25 core loads first (latency hides under staging) ----
  const int g = ((b * 8 + n) * 256 + y) * 64 + xh * 32 + q;   // global 4-px group
  const f4* c4 = (const f4*)(core + (size_t)g * 100);
  float ws[100];
#pragma unroll
  for (int k = 0; k < 25; ++k) {
    f4 t = __builtin_nontemporal_load(c4 + k);
    ws[4 * k + 0] = t[0]; ws[4 * k + 1] = t[1];
    ws[4 * k + 2] = t[2]; ws[4 * k + 3] = t[3];
  }

  // ---- cooperative frame staging: 8 n x 5 rows x 34 float4 ----
  for (int i = tid; i < 8 * 5 * 34; i += 256) {
    const int nn  = i / 170;           // 170 = 5*34
    const int rem = i - nn * 170;
    const int r   = rem / 34;
    const int c   = rem - r * 34;
    const int yy  = y + r - 2;
    const int x4  = xh * 128 + (c - 1) * 4;   // -4 .. 256 (float4-aligned)
    f4 v = {0.f, 0.f, 0.f, 0.f};
    if ((unsigned)yy < (unsigned)H && (unsigned)x4 <= 252u) {
      v = *(const f4*)(frames + ((size_t)(b * 8 + nn) * H + yy) * W + x4);
    }
    smem[i] = v;
  }
  __syncthreads();

  // ---- compute: 25 taps x 4 pixels ----
  f4 acc = {0.f, 0.f, 0.f, 0.f};
#pragma unroll
  for (int ki = 0; ki < 5; ++ki) {
    const f4* row = &smem[(n * 5 + ki) * 34 + q];   // covers x0-4 .. x0+7
    f4 a0 = row[0], a1 = row[1], a2 = row[2];
    float fr[12] = {a0[0], a0[1], a0[2], a0[3],
                    a1[0], a1[1], a1[2], a1[3],
                    a2[0], a2[1], a2[2], a2[3]};
#pragma unroll
    for (int kj = 0; kj < 5; ++kj) {
#pragma unroll
      for (int p = 0; p < 4; ++p) {
        acc[p] += ws[p * 25 + ki * 5 + kj] * fr[p + kj + 2];
      }
    }
  }
  __builtin_nontemporal_store(acc, (f4*)(pred_i + (size_t)g * 4));

  // ---- block-level mean over n -> pred ----
  __syncthreads();                     // all LDS frame reads done; reuse smem
  f4* red = smem;
  red[tid] = acc;
  __syncthreads();
  if (tid < 32) {
    f4 s = {0.f, 0.f, 0.f, 0.f};
#pragma unroll
    for (int k = 0; k < 8; ++k) {
      s += red[tid + 32 * k];
    }
    s *= 0.125f;
    __builtin_nontemporal_store(
        s, (f4*)(pred + ((size_t)b * 256 + y) * 256 + xh * 128 + tid * 4));
  }
}

extern "C" void kernel_launch(void* const* d_in, const int* in_sizes, int n_in,
                              void* d_out, int out_size, void* d_ws, size_t ws_size,
                              hipStream_t stream) {
  const float* frames = (const float*)d_in[0];
  const float* core   = (const float*)d_in[1];
  float* pred   = (float*)d_out;                     // (4,256,256,1)
  float* pred_i = pred + (size_t)4 * H * W;          // (4,8,256,256,1)

  hipLaunchKernelGGL(kpn_fused, dim3(2048), dim3(256), 0, stream,
                     frames, core, pred, pred_i);
}

// Round 4
// 44.090 us; speedup vs baseline: 3.0530x; 3.0530x over previous
//
#include <hip/hip_runtime.h>

// Shapes (fixed by the reference):
//   frames: (4, 8, 256, 256, 1) f32
//   core:   (4, 256, 256, 200)  f32  -> raw-reshaped to (4, 8, 256, 256, 1, 25)
//   out:    pred_img (4,256,256,1) ++ pred_img_i (4,8,256,256,1), f32
//
// Fused single kernel: block = (b, y, half-row of 128 px) x ALL 8 burst frames.
// n = tid>>5, q = tid&31 (4 px/thread). Computes pred_img_i for all n, then a
// block-level LDS reduction produces pred_img (no second kernel; pred_img_i is
// write-only). The 25 per-thread core float4 loads are issued up-front and
// pinned there with sched_barrier(0) so all 25 stay in flight (MLP) while the
// frame staging runs -- R3 showed the scheduler otherwise sinks them into the
// FMA loop (VGPR 60, VALUBusy 3%, latency-bound).
#define H 256
#define W 256

typedef float f4 __attribute__((ext_vector_type(4)));

__global__ __launch_bounds__(256, 3)
void kpn_fused(const float* __restrict__ frames, const float* __restrict__ core,
               float* __restrict__ pred, float* __restrict__ pred_i) {
  // frame staging [n][r][c]: 8 frames x 5 rows x 34 float4 (x = xh*128-4 .. +131)
  __shared__ f4 smem[8 * 5 * 34];      // 21760 B; first 256 slots reused for reduction

  const int tid = threadIdx.x;
  const int blk = blockIdx.x;          // b*512 + y*2 + xh
  const int xh  = blk & 1;
  const int y   = (blk >> 1) & 255;
  const int b   = blk >> 9;

  const int n = tid >> 5;              // burst frame 0..7
  const int q = tid & 31;              // 4-pixel group within the 128-px half-row

  // ---- issue ALL 25 core loads first; pin them here ----
  const int g = ((b * 8 + n) * 256 + y) * 64 + xh * 32 + q;   // global 4-px group
  const f4* c4 = (const f4*)(core + (size_t)g * 100);
  f4 wv[25];
#pragma unroll
  for (int k = 0; k < 25; ++k) {
    wv[k] = c4[k];
  }
  __builtin_amdgcn_sched_barrier(0);   // do NOT sink these loads past staging

  // ---- cooperative frame staging: 8 n x 5 rows x 34 float4 ----
  for (int i = tid; i < 8 * 5 * 34; i += 256) {
    const int nn  = i / 170;           // 170 = 5*34
    const int rem = i - nn * 170;
    const int r   = rem / 34;
    const int c   = rem - r * 34;
    const int yy  = y + r - 2;
    const int x4  = xh * 128 + (c - 1) * 4;   // -4 .. 256 (float4-aligned)
    f4 v = {0.f, 0.f, 0.f, 0.f};
    if ((unsigned)yy < (unsigned)H && (unsigned)x4 <= 252u) {
      v = *(const f4*)(frames + ((size_t)(b * 8 + nn) * H + yy) * W + x4);
    }
    smem[i] = v;
  }
  __syncthreads();

  // ---- compute: 25 taps x 4 pixels ----
  f4 acc = {0.f, 0.f, 0.f, 0.f};
#pragma unroll
  for (int ki = 0; ki < 5; ++ki) {
    const f4* row = &smem[(n * 5 + ki) * 34 + q];   // covers x0-4 .. x0+7
    f4 a0 = row[0], a1 = row[1], a2 = row[2];
    float fr[12] = {a0[0], a0[1], a0[2], a0[3],
                    a1[0], a1[1], a1[2], a1[3],
                    a2[0], a2[1], a2[2], a2[3]};
#pragma unroll
    for (int kj = 0; kj < 5; ++kj) {
#pragma unroll
      for (int p = 0; p < 4; ++p) {
        const int f = p * 25 + ki * 5 + kj;         // compile-time constant
        acc[p] += wv[f >> 2][f & 3] * fr[p + kj + 2];
      }
    }
  }
  __builtin_nontemporal_store(acc, (f4*)(pred_i + (size_t)g * 4));

  // ---- block-level mean over n -> pred ----
  __syncthreads();                     // all LDS frame reads done; reuse smem
  f4* red = smem;
  red[tid] = acc;
  __syncthreads();
  if (tid < 32) {
    f4 s = {0.f, 0.f, 0.f, 0.f};
#pragma unroll
    for (int k = 0; k < 8; ++k) {
      s += red[tid + 32 * k];
    }
    s *= 0.125f;
    __builtin_nontemporal_store(
        s, (f4*)(pred + ((size_t)b * 256 + y) * 256 + xh * 128 + tid * 4));
  }
}

extern "C" void kernel_launch(void* const* d_in, const int* in_sizes, int n_in,
                              void* d_out, int out_size, void* d_ws, size_t ws_size,
                              hipStream_t stream) {
  const float* frames = (const float*)d_in[0];
  const float* core   = (const float*)d_in[1];
  float* pred   = (float*)d_out;                     // (4,256,256,1)
  float* pred_i = pred + (size_t)4 * H * W;          // (4,8,256,256,1)

  hipLaunchKernelGGL(kpn_fused, dim3(2048), dim3(256), 0, stream,
                     frames, core, pred, pred_i);
}